// Round 10
// baseline (363.568 us; speedup 1.0000x reference)
//
#include <hip/hip_runtime.h>
#include <hip/hip_bf16.h>
#include <math.h>

#define DIM     1024
#define NHEADS  16
#define HD      64
#define BATCH   4
#define SEQ     2048
#define M_TOT   (BATCH * SEQ)   // 8192
#define QSCALE  0.180336880111f  // 0.125 * log2(e): softmax via exp2

using short8 = __attribute__((ext_vector_type(8))) short;   // 8 bf16 (4 VGPRs)
using bf16x4 = __attribute__((ext_vector_type(4))) short;   // 4 bf16 (2 VGPRs)
using f32x4  = __attribute__((ext_vector_type(4))) float;   // MFMA accumulator

__device__ inline unsigned short f2bf(float x) {
    __hip_bfloat16 h = __float2bfloat16(x);
    unsigned short u;
    __builtin_memcpy(&u, &h, sizeof(u));
    return u;
}
__device__ inline void st_o(float* p, float v)          { *p = v; }
__device__ inline void st_o(unsigned short* p, float v) { *p = f2bf(v); }

// pack 2 finite-positive floats to 2 bf16 (round-half-up), 3 VALU ops
__device__ inline unsigned pk2bf(float a, float b) {
    unsigned ua, ub;
    __builtin_memcpy(&ua, &a, 4); __builtin_memcpy(&ub, &b, 4);
    ua += 0x8000u; ub += 0x8000u;
    return (ua >> 16) | (ub & 0xffff0000u);
}

// async global->LDS, 16B per lane; lds ptr must be wave-uniform (lane l lands
// at lds + l*16 per HW rule); global ptr is per-lane.
__device__ inline void async16(const void* g, void* l) {
    __builtin_amdgcn_global_load_lds(
        (const __attribute__((address_space(1))) void*)g,
        (__attribute__((address_space(3))) void*)l, 16, 0, 0);
}

// ---------- fp32 -> bf16 convert, 3 tensors in one launch ----------
__global__ __launch_bounds__(256) void cvt3(
    const float* __restrict__ S0, const float* __restrict__ S1,
    const float* __restrict__ S2,
    unsigned short* __restrict__ D0, unsigned short* __restrict__ D1,
    unsigned short* __restrict__ D2)
{
    const float* src; unsigned short* dst;
    switch (blockIdx.y) {
        case 0:  src = S0; dst = D0; break;
        case 1:  src = S1; dst = D1; break;
        default: src = S2; dst = D2; break;
    }
    const size_t i = ((size_t)blockIdx.x * 256 + threadIdx.x) * 16;
    unsigned short tmp[16];
    #pragma unroll
    for (int p = 0; p < 4; ++p) {
        const float4 v = *(const float4*)(src + i + p * 4);
        tmp[p * 4 + 0] = f2bf(v.x); tmp[p * 4 + 1] = f2bf(v.y);
        tmp[p * 4 + 2] = f2bf(v.z); tmp[p * 4 + 3] = f2bf(v.w);
    }
    *(short8*)(dst + i)     = *(short8*)&tmp[0];
    *(short8*)(dst + i + 8) = *(short8*)&tmp[8];
}

// ---------- weight convert + transpose, 4 weights in one launch ----------
// Wt[n][k] = bf16(W[k][n])
__global__ __launch_bounds__(256) void wcvt4(
    const float* __restrict__ W0, const float* __restrict__ W1,
    const float* __restrict__ W2, const float* __restrict__ W3,
    unsigned short* __restrict__ T0, unsigned short* __restrict__ T1,
    unsigned short* __restrict__ T2, unsigned short* __restrict__ T3)
{
    const float* W; unsigned short* Wt;
    switch (blockIdx.z) {
        case 0:  W = W0; Wt = T0; break;
        case 1:  W = W1; Wt = T1; break;
        case 2:  W = W2; Wt = T2; break;
        default: W = W3; Wt = T3; break;
    }
    __shared__ unsigned short tile[32][33];
    const int t = threadIdx.x;
    const int tx = t & 31, ty = t >> 5;              // 32 x 8
    const int n0 = blockIdx.x * 32, k0 = blockIdx.y * 32;
    #pragma unroll
    for (int i = 0; i < 4; ++i) {
        const int kk = ty + i * 8;
        tile[kk][tx] = f2bf(W[(size_t)(k0 + kk) * DIM + n0 + tx]);
    }
    __syncthreads();
    #pragma unroll
    for (int i = 0; i < 4; ++i) {
        const int nn = ty + i * 8;
        Wt[(size_t)(n0 + nn) * DIM + k0 + tx] = tile[tx][nn];
    }
}

// ---------- MFMA GEMM body: Y = (A @ Wt^T + bias) * scale ----------
// A: [M][1024] bf16, Wt: [N=1024][K=1024] bf16. 128x128 tile, BK=32,
// 4 waves (2x2), global_load_lds 16B staging.
// Single-barrier double-buffered K-loop: issue next-tile DMA into buf^1,
// compute buf, ONE __syncthreads per step (drains vmcnt -> DMA resident +
// all reads of buf done). XCD-bijective block swizzle: grid.x is always 8
// (DIM/128) and nwg=512 (%8==0); XCD k gets a contiguous run of 64 tiles
// (8 m-tiles sharing Wt 2MB + A 2MB -> L2-resident).
// TRANSV: write output directly in vt layout vt[(b*16+h)*64+d][s]; acc
// quad = 4 consecutive m-rows = 4 consecutive s for one (h,d).
template <typename TY, bool TRANSV>
__device__ __forceinline__ void gemm_body(
    const unsigned short* A, const unsigned short* Wt,
    const float* bias, TY* Y, float scale,
    unsigned short* As, unsigned short* Bs)    // each [2][128*32]
{
    const int t = threadIdx.x;
    const int lane = t & 63, wv = t >> 6;
    const int wm = wv >> 1, wn = wv & 1;
    const int l16 = lane & 15, lq = lane >> 4;

    // XCD swizzle (bijective, per z-slice): lin%8 = XCD; slot = contiguous
    // tile index within the XCD, n-fastest (grid.x == 8 hardcoded).
    const unsigned lin = blockIdx.y * 8 + blockIdx.x;   // gridDim.x == 8
    const unsigned wg  = (lin & 7) * 64 + (lin >> 3);   // nwg=512, 64 per XCD
    const int m0 = (int)(wg >> 3) * 128, n0 = (int)(wg & 7) * 128;

    const int lrow = lane >> 2;            // 0..15 within 16-row chunk
    const int lcol = (lane & 3) * 8;       // k-elem offset (16B granules)

    f32x4 acc[4][4] = {};

    // prologue: stage k-tile 0 into buffer 0
    #pragma unroll
    for (int c = 0; c < 2; ++c) {
        const int ci  = wv * 2 + c;                    // chunk 0..7 (16 rows)
        const int row = ci * 16 + lrow;
        async16(A  + (size_t)(m0 + row) * DIM + lcol, &As[ci * 512]);
        async16(Wt + (size_t)(n0 + row) * DIM + lcol, &Bs[ci * 512]);
    }
    __syncthreads();   // vmcnt drained -> tile 0 resident

    int cur = 0;
    for (int k0 = 0; k0 < DIM; k0 += 32) {
        // issue next-tile DMA first; latency hides under frag reads + MFMA
        if (k0 + 32 < DIM) {
            unsigned short* Ad = As + (cur ^ 1) * 4096;
            unsigned short* Bd = Bs + (cur ^ 1) * 4096;
            #pragma unroll
            for (int c = 0; c < 2; ++c) {
                const int ci  = wv * 2 + c;
                const int row = ci * 16 + lrow;
                async16(A  + (size_t)(m0 + row) * DIM + k0 + 32 + lcol, Ad + ci * 512);
                async16(Wt + (size_t)(n0 + row) * DIM + k0 + 32 + lcol, Bd + ci * 512);
            }
        }
        const unsigned short* Ac = As + cur * 4096;
        const unsigned short* Bc = Bs + cur * 4096;

        short8 af[4], bfr[4];
        #pragma unroll
        for (int mi = 0; mi < 4; ++mi)
            af[mi] = *(const short8*)&Ac[(wm * 64 + mi * 16 + l16) * 32 + lq * 8];
        #pragma unroll
        for (int nj = 0; nj < 4; ++nj)
            bfr[nj] = *(const short8*)&Bc[(wn * 64 + nj * 16 + l16) * 32 + lq * 8];
        #pragma unroll
        for (int mi = 0; mi < 4; ++mi)
            #pragma unroll
            for (int nj = 0; nj < 4; ++nj)
                acc[mi][nj] = __builtin_amdgcn_mfma_f32_16x16x32_bf16(
                    af[mi], bfr[nj], acc[mi][nj], 0, 0, 0);

        __syncthreads();   // drains DMA (next tile ready) + all reads of cur done
        cur ^= 1;
    }

    #pragma unroll
    for (int mi = 0; mi < 4; ++mi)
        #pragma unroll
        for (int nj = 0; nj < 4; ++nj) {
            const int row = m0 + wm * 64 + mi * 16 + lq * 4;
            const int col = n0 + wn * 64 + nj * 16 + l16;
            const float bb = bias[col];
            if constexpr (TRANSV) {
                unsigned short o[4];
                #pragma unroll
                for (int r = 0; r < 4; ++r)
                    o[r] = f2bf((acc[mi][nj][r] + bb) * scale);
                const int bb_ = row >> 11, ss = row & (SEQ - 1);   // b, s
                unsigned short* dst = (unsigned short*)Y +
                    ((size_t)(bb_ * NHEADS + (col >> 6)) * HD + (col & 63)) * SEQ + ss;
                *(bf16x4*)dst = *(const bf16x4*)o;
            } else {
                #pragma unroll
                for (int r = 0; r < 4; ++r)
                    st_o(&Y[(size_t)(row + r) * DIM + col],
                         (acc[mi][nj][r] + bb) * scale);
            }
        }
}

template <typename TY, bool TRANSV = false>
__global__ __launch_bounds__(256) void gemm_a16(
    const unsigned short* __restrict__ A, const unsigned short* __restrict__ Wt,
    const float* __restrict__ bias, TY* __restrict__ Y, float scale)
{
    __shared__ unsigned short As[2 * 128 * 32];
    __shared__ unsigned short Bs[2 * 128 * 32];
    gemm_body<TY, TRANSV>(A, Wt, bias, Y, scale, As, Bs);
}

// Fused V+Q+K projections: blockIdx.z selects the unit. 1536 blocks ->
// full-chip TLP for the whole projection phase. All reads/writes of the
// three units are disjoint buffers (qf goes to d_out scratch).
__global__ __launch_bounds__(256) void gemm_qkv(
    const unsigned short* Av, const unsigned short* Wtv, const float* bv_,
    unsigned short* Yv,
    const unsigned short* Aq, const unsigned short* Wtq, const float* bq_,
    unsigned short* Yq,
    const unsigned short* Ak, const unsigned short* Wtk, const float* bk_,
    unsigned short* Yk)
{
    __shared__ unsigned short As[2 * 128 * 32];
    __shared__ unsigned short Bs[2 * 128 * 32];
    const int z = blockIdx.z;
    if (z == 0)
        gemm_body<unsigned short, true >(Av, Wtv, bv_, Yv, 1.0f,   As, Bs);
    else if (z == 1)
        gemm_body<unsigned short, false>(Aq, Wtq, bq_, Yq, QSCALE, As, Bs);
    else
        gemm_body<unsigned short, false>(Ak, Wtk, bk_, Yk, 1.0f,   As, Bs);
}

// ---------- MFMA flash attention v11 ----------
// qf: pre-scaled bf16 [B,S,DIM] (d_out scratch); kf: bf16 [B,S,DIM];
// vt: bf16 [B*H][64][S]; ctx -> separate buffer (no aliasing).
// v11 = v10 + PV accumulator-chain split (O[8]: even ti -> O[0..3], odd
// ti -> O[4..7]; merged after the loop) to double MFMA ILP on the PV
// dependency chains, + per-ti row-sum partials la[4] (no serial chain),
// + setprio windows covering only the MFMA clusters (m191 recipe).
__global__ __launch_bounds__(256) void attn_mfma(
    const unsigned short* __restrict__ qbuf, const unsigned short* __restrict__ kbuf,
    const unsigned short* __restrict__ vtb, unsigned short* __restrict__ ctx)
{
    __shared__ unsigned short Kls[2 * 64 * 64];   // [buf][s][d], granule-swizzled
    __shared__ unsigned short Vls[2 * 64 * 64];   // [buf][d][s], granule-swizzled
    __shared__ unsigned short Qls[64 * 64];       // [q][d],      granule-swizzled

    const int t = threadIdx.x;
    const int lane = t & 63, wv = t >> 6;
    const int l16 = lane & 15, lq = lane >> 4;
    const int l7 = l16 & 7;
    const int lqh = lq >> 1, lql4 = (lq & 1) * 4;

    // XCD swizzle (bijective): all 32 q-blocks of a (b,h) share lin%8.
    const unsigned lin  = (blockIdx.z * gridDim.y + blockIdx.y) * gridDim.x + blockIdx.x;
    const unsigned xcd  = lin & 7, slot = lin >> 3;
    const unsigned bh   = ((slot >> 5) << 3) | xcd;
    const int b = (int)(bh >> 4), h = (int)(bh & 15);
    const int q0 = (int)(slot & 31) * 64;

    const size_t base  = ((size_t)b * SEQ) * DIM + h * HD;
    const size_t vbase = ((size_t)(b * NHEADS + h)) * HD * SEQ;

    // async16 staging geometry: chunk = 8 rows x 128B; lane l covers
    // row rl = l>>3, dest granule l&7. Source granule pre-swizzled by
    // XOR with (row&7) so reads use the same involution.
    const int rl   = lane >> 3;
    const int gcol = ((lane & 7) ^ rl) << 3;   // source col offset (elems)

    {   // stage Q tile, swizzled plain stores (wave-local rows, no barrier)
        const int r = t >> 2, c = (t & 3) * 16;       // r in wave's own 16 rows
        const int g0 = c >> 3, rx = r & 7;
        const unsigned short* src = qbuf + base + (size_t)(q0 + r) * DIM + c;
        *(short8*)&Qls[r * 64 + ((g0 ^ rx) << 3)]       = *(const short8*)src;
        *(short8*)&Qls[r * 64 + (((g0 + 1) ^ rx) << 3)] = *(const short8*)(src + 8);
    }
    // Q fragments (same XOR involution); B-operand of swapped QK
    const int qrow = wv * 16 + l16;
    const short8 qf0 = *(const short8*)&Qls[qrow * 64 + ((lq ^ l7) << 3)];
    const short8 qf1 = *(const short8*)&Qls[qrow * 64 + (((4 + lq) ^ l7) << 3)];

    float la[4] = {0.f, 0.f, 0.f, 0.f};
    f32x4 O[8] = {};

    // prologue: stage K/V tile 0 into buffer 0 (2 K-chunks + 2 V-chunks/wave)
    #pragma unroll
    for (int c = 0; c < 2; ++c) {
        const int ci = wv * 2 + c;
        async16(kbuf + base + (size_t)(ci * 8 + rl) * DIM + gcol, Kls + ci * 512);
        async16(vtb + vbase + (size_t)(ci * 8 + rl) * SEQ + gcol, Vls + ci * 512);
    }
    __syncthreads();   // vmcnt drained before barrier -> tile 0 resident

    int cur = 0;
    for (int s0 = 0; s0 < SEQ; s0 += 64) {
        const unsigned short* Kc = Kls + cur * 4096;
        const unsigned short* Vc = Vls + cur * 4096;

        // issue next-tile DMA first; latency hides under QK+softmax+PV
        if (s0 + 64 < SEQ) {
            unsigned short* Kd = Kls + (cur ^ 1) * 4096;
            unsigned short* Vd = Vls + (cur ^ 1) * 4096;
            #pragma unroll
            for (int c = 0; c < 2; ++c) {
                const int ci = wv * 2 + c;
                async16(kbuf + base + (size_t)(s0 + 64 + ci * 8 + rl) * DIM + gcol,
                        Kd + ci * 512);
                async16(vtb + vbase + (size_t)(ci * 8 + rl) * SEQ + s0 + 64 + gcol,
                        Vd + ci * 512);
            }
        }

        // S'^T = K Q^T : C[row = s = lq*4+r (per ti), col = q = l16]
        f32x4 sa[4] = {};
        __builtin_amdgcn_s_setprio(1);
        #pragma unroll
        for (int ti = 0; ti < 4; ++ti) {
            const int rr = ti * 16 + l16;
            const short8 kf0 = *(const short8*)(Kc + rr * 64 + ((lq ^ l7) << 3));
            const short8 kf1 = *(const short8*)(Kc + rr * 64 + (((4 + lq) ^ l7) << 3));
            sa[ti] = __builtin_amdgcn_mfma_f32_16x16x32_bf16(kf0, qf0, sa[ti], 0, 0, 0);
            sa[ti] = __builtin_amdgcn_mfma_f32_16x16x32_bf16(kf1, qf1, sa[ti], 0, 0, 0);
        }
        __builtin_amdgcn_s_setprio(0);

        // p = 2^s' in-register; this IS the 16x16x16 A-frag (k = lq*4+e).
        // Even ti accumulate into O[0..3], odd ti into O[4..7]: 8 chains.
        __builtin_amdgcn_s_setprio(1);
        #pragma unroll
        for (int ti = 0; ti < 4; ++ti) {
            const float v0 = __builtin_amdgcn_exp2f(sa[ti][0]);
            const float v1 = __builtin_amdgcn_exp2f(sa[ti][1]);
            const float v2 = __builtin_amdgcn_exp2f(sa[ti][2]);
            const float v3 = __builtin_amdgcn_exp2f(sa[ti][3]);
            la[ti] += (v0 + v1) + (v2 + v3);
            unsigned pw[2] = { pk2bf(v0, v1), pk2bf(v2, v3) };
            bf16x4 pa;
            __builtin_memcpy(&pa, pw, 8);
            #pragma unroll
            for (int dt = 0; dt < 4; ++dt) {
                const int vr = dt * 16 + l16;
                const bf16x4 vb = *(const bf16x4*)(
                    Vc + vr * 64 + (((2 * ti + lqh) ^ l7) << 3) + lql4);
                O[(ti & 1) * 4 + dt] = __builtin_amdgcn_mfma_f32_16x16x16bf16_1k(
                    pa, vb, O[(ti & 1) * 4 + dt], 0, 0, 0);
            }
        }
        __builtin_amdgcn_s_setprio(0);

        __syncthreads();   // drains DMA (next tile ready) + all reads of cur done
        cur ^= 1;
    }

    // merge the two accumulator banks
    #pragma unroll
    for (int dt = 0; dt < 4; ++dt)
        #pragma unroll
        for (int r = 0; r < 4; ++r)
            O[dt][r] += O[4 + dt][r];

    // row sums: lane partial covers q = wv*16+l16 over s ≡ {lq*4+0..3} (+16k);
    // reduce across the 4 lq groups -> every lane holds S(q = wv*16+l16).
    float l_acc = (la[0] + la[1]) + (la[2] + la[3]);
    l_acc += __shfl_xor(l_acc, 16);
    l_acc += __shfl_xor(l_acc, 32);

    // O rows are q = wv*16 + lq*4 + r -> fetch that row's sum from lane lq*4+r.
    unsigned short (*Ol)[72] = (unsigned short(*)[72])Kls;   // reuse K LDS
    #pragma unroll
    for (int r = 0; r < 4; ++r) {
        const float inv = 1.0f / __shfl(l_acc, lq * 4 + r);
        const int orow = wv * 16 + lq * 4 + r;
        #pragma unroll
        for (int dt = 0; dt < 4; ++dt)
            Ol[orow][dt * 16 + l16] = f2bf(O[dt][r] * inv);
    }
    __syncthreads();
    {
        const int r = t >> 2, c = (t & 3) * 16;
        unsigned short* dst = ctx + base + (size_t)(q0 + r) * DIM + c;
        *(short8*)dst       = *(const short8*)&Ol[r][c];
        *(short8*)(dst + 8) = *(const short8*)&Ol[r][c + 8];
    }
}

extern "C" void kernel_launch(void* const* d_in, const int* in_sizes, int n_in,
                              void* d_out, int out_size, void* d_ws, size_t ws_size,
                              hipStream_t stream) {
    const float* Q  = (const float*)d_in[0];
    const float* K  = (const float*)d_in[1];
    const float* V  = (const float*)d_in[2];
    const float* Wq = (const float*)d_in[3];
    const float* bq = (const float*)d_in[4];
    const float* Wk = (const float*)d_in[5];
    const float* bk = (const float*)d_in[6];
    const float* Wv = (const float*)d_in[7];
    const float* bv = (const float*)d_in[8];
    const float* Wo = (const float*)d_in[9];
    const float* bo = (const float*)d_in[10];
    float* out = (float*)d_out;

    // ws: 4 weights (2 MB ea) + 5 x 16 MB buffers = 88 MB.
    // Buffer plan (lifetimes disjoint in stream order; every byte rewritten
    // every launch before any read -> replay-safe):
    //   bufA: vb -> ctx        bufB: kb        bufC: qb
    //   bufD: kf               bufE: vt
    //   d_out: qf scratch (bf16, first 16 MB) -> final f32 output
    const size_t eW = (size_t)DIM * DIM;     // 1M elems
    const size_t eB = (size_t)M_TOT * DIM;   // 8M elems
    unsigned short* p   = (unsigned short*)d_ws;
    unsigned short* wtq = p; p += eW;
    unsigned short* wtk = p; p += eW;
    unsigned short* wtv = p; p += eW;
    unsigned short* wto = p; p += eW;
    unsigned short* bufA = p; p += eB;
    unsigned short* bufB = p; p += eB;
    unsigned short* bufC = p; p += eB;
    unsigned short* bufD = p; p += eB;
    unsigned short* bufE = p;
    unsigned short* qfs = (unsigned short*)out;   // d_out scratch

    wcvt4<<<dim3(32, 32, 4), 256, 0, stream>>>(Wq, Wk, Wv, Wo, wtq, wtk, wtv, wto);

    const int cvt_blocks = (int)(eB / (256 * 16));   // 2048
    cvt3<<<dim3(cvt_blocks, 3), 256, 0, stream>>>(V, Q, K, bufA, bufC, bufB);

    // fused V+Q+K projections: reads {bufA,bufC,bufB,wt*}, writes {bufE,qfs,bufD}
    gemm_qkv<<<dim3(DIM / 128, M_TOT / 128, 3), 256, 0, stream>>>(
        bufA, wtv, bv, bufE,     // z=0: vt (TRANSV epilogue)
        bufC, wtq, bq, qfs,      // z=1: qf -> d_out scratch
        bufB, wtk, bk, bufD);    // z=2: kf

    attn_mfma<<<dim3(SEQ / 64, NHEADS, BATCH), 256, 0, stream>>>(qfs, bufD, bufE, bufA);

    gemm_a16<float><<<dim3(DIM / 128, M_TOT / 128), 256, 0, stream>>>(
        bufA, wto, bo, out, 1.0f);
}

// Round 11
// 361.147 us; speedup vs baseline: 1.0067x; 1.0067x over previous
//
#include <hip/hip_runtime.h>
#include <hip/hip_bf16.h>
#include <math.h>

#define DIM     1024
#define NHEADS  16
#define HD      64
#define BATCH   4
#define SEQ     2048
#define M_TOT   (BATCH * SEQ)   // 8192
#define QSCALE  0.180336880111f  // 0.125 * log2(e): softmax via exp2

using short8 = __attribute__((ext_vector_type(8))) short;   // 8 bf16 (4 VGPRs)
using bf16x4 = __attribute__((ext_vector_type(4))) short;   // 4 bf16 (2 VGPRs)
using f32x4  = __attribute__((ext_vector_type(4))) float;   // MFMA accumulator

__device__ inline unsigned short f2bf(float x) {
    __hip_bfloat16 h = __float2bfloat16(x);
    unsigned short u;
    __builtin_memcpy(&u, &h, sizeof(u));
    return u;
}
__device__ inline void st_o(float* p, float v)          { *p = v; }
__device__ inline void st_o(unsigned short* p, float v) { *p = f2bf(v); }

// pack 2 finite-positive floats to 2 bf16 (round-half-up), 3 VALU ops
__device__ inline unsigned pk2bf(float a, float b) {
    unsigned ua, ub;
    __builtin_memcpy(&ua, &a, 4); __builtin_memcpy(&ub, &b, 4);
    ua += 0x8000u; ub += 0x8000u;
    return (ua >> 16) | (ub & 0xffff0000u);
}

// async global->LDS, 16B per lane; lds ptr must be wave-uniform (lane l lands
// at lds + l*16 per HW rule); global ptr is per-lane.
__device__ inline void async16(const void* g, void* l) {
    __builtin_amdgcn_global_load_lds(
        (const __attribute__((address_space(1))) void*)g,
        (__attribute__((address_space(3))) void*)l, 16, 0, 0);
}

// ---------- fp32 -> bf16 convert, 3 tensors in one launch ----------
__global__ __launch_bounds__(256) void cvt3(
    const float* __restrict__ S0, const float* __restrict__ S1,
    const float* __restrict__ S2,
    unsigned short* __restrict__ D0, unsigned short* __restrict__ D1,
    unsigned short* __restrict__ D2)
{
    const float* src; unsigned short* dst;
    switch (blockIdx.y) {
        case 0:  src = S0; dst = D0; break;
        case 1:  src = S1; dst = D1; break;
        default: src = S2; dst = D2; break;
    }
    const size_t i = ((size_t)blockIdx.x * 256 + threadIdx.x) * 16;
    unsigned short tmp[16];
    #pragma unroll
    for (int p = 0; p < 4; ++p) {
        const float4 v = *(const float4*)(src + i + p * 4);
        tmp[p * 4 + 0] = f2bf(v.x); tmp[p * 4 + 1] = f2bf(v.y);
        tmp[p * 4 + 2] = f2bf(v.z); tmp[p * 4 + 3] = f2bf(v.w);
    }
    *(short8*)(dst + i)     = *(short8*)&tmp[0];
    *(short8*)(dst + i + 8) = *(short8*)&tmp[8];
}

// ---------- weight convert + transpose, 4 weights in one launch ----------
// Wt[n][k] = bf16(W[k][n])
__global__ __launch_bounds__(256) void wcvt4(
    const float* __restrict__ W0, const float* __restrict__ W1,
    const float* __restrict__ W2, const float* __restrict__ W3,
    unsigned short* __restrict__ T0, unsigned short* __restrict__ T1,
    unsigned short* __restrict__ T2, unsigned short* __restrict__ T3)
{
    const float* W; unsigned short* Wt;
    switch (blockIdx.z) {
        case 0:  W = W0; Wt = T0; break;
        case 1:  W = W1; Wt = T1; break;
        case 2:  W = W2; Wt = T2; break;
        default: W = W3; Wt = T3; break;
    }
    __shared__ unsigned short tile[32][33];
    const int t = threadIdx.x;
    const int tx = t & 31, ty = t >> 5;              // 32 x 8
    const int n0 = blockIdx.x * 32, k0 = blockIdx.y * 32;
    #pragma unroll
    for (int i = 0; i < 4; ++i) {
        const int kk = ty + i * 8;
        tile[kk][tx] = f2bf(W[(size_t)(k0 + kk) * DIM + n0 + tx]);
    }
    __syncthreads();
    #pragma unroll
    for (int i = 0; i < 4; ++i) {
        const int nn = ty + i * 8;
        Wt[(size_t)(n0 + nn) * DIM + k0 + tx] = tile[tx][nn];
    }
}

// ---------- MFMA GEMM body: Y = (A @ Wt^T + bias) * scale ----------
// A: [M][1024] bf16, Wt: [N=1024][K=1024] bf16. 128x128 tile, BK=32,
// 4 waves (2x2), global_load_lds 16B staging.
// Single-barrier double-buffered K-loop + XCD-bijective block swizzle
// (grid.x == 8, nwg = 512 -> 64 contiguous tiles per XCD, L2-resident).
// TRANSV: write output directly in vt layout vt[(b*16+h)*64+d][s]; acc
// quad = 4 consecutive m-rows = 4 consecutive s for one (h,d).
template <typename TY, bool TRANSV>
__device__ __forceinline__ void gemm_body(
    const unsigned short* A, const unsigned short* Wt,
    const float* bias, TY* Y, float scale,
    unsigned short* As, unsigned short* Bs)    // each [2][128*32]
{
    const int t = threadIdx.x;
    const int lane = t & 63, wv = t >> 6;
    const int wm = wv >> 1, wn = wv & 1;
    const int l16 = lane & 15, lq = lane >> 4;

    // XCD swizzle (bijective, per z-slice): lin%8 = XCD; slot = contiguous
    // tile index within the XCD, n-fastest (grid.x == 8 hardcoded).
    const unsigned lin = blockIdx.y * 8 + blockIdx.x;   // gridDim.x == 8
    const unsigned wg  = (lin & 7) * 64 + (lin >> 3);   // nwg=512, 64 per XCD
    const int m0 = (int)(wg >> 3) * 128, n0 = (int)(wg & 7) * 128;

    const int lrow = lane >> 2;            // 0..15 within 16-row chunk
    const int lcol = (lane & 3) * 8;       // k-elem offset (16B granules)

    f32x4 acc[4][4] = {};

    // prologue: stage k-tile 0 into buffer 0
    #pragma unroll
    for (int c = 0; c < 2; ++c) {
        const int ci  = wv * 2 + c;                    // chunk 0..7 (16 rows)
        const int row = ci * 16 + lrow;
        async16(A  + (size_t)(m0 + row) * DIM + lcol, &As[ci * 512]);
        async16(Wt + (size_t)(n0 + row) * DIM + lcol, &Bs[ci * 512]);
    }
    __syncthreads();   // vmcnt drained -> tile 0 resident

    int cur = 0;
    for (int k0 = 0; k0 < DIM; k0 += 32) {
        // issue next-tile DMA first; latency hides under frag reads + MFMA
        if (k0 + 32 < DIM) {
            unsigned short* Ad = As + (cur ^ 1) * 4096;
            unsigned short* Bd = Bs + (cur ^ 1) * 4096;
            #pragma unroll
            for (int c = 0; c < 2; ++c) {
                const int ci  = wv * 2 + c;
                const int row = ci * 16 + lrow;
                async16(A  + (size_t)(m0 + row) * DIM + k0 + 32 + lcol, Ad + ci * 512);
                async16(Wt + (size_t)(n0 + row) * DIM + k0 + 32 + lcol, Bd + ci * 512);
            }
        }
        const unsigned short* Ac = As + cur * 4096;
        const unsigned short* Bc = Bs + cur * 4096;

        short8 af[4], bfr[4];
        #pragma unroll
        for (int mi = 0; mi < 4; ++mi)
            af[mi] = *(const short8*)&Ac[(wm * 64 + mi * 16 + l16) * 32 + lq * 8];
        #pragma unroll
        for (int nj = 0; nj < 4; ++nj)
            bfr[nj] = *(const short8*)&Bc[(wn * 64 + nj * 16 + l16) * 32 + lq * 8];
        #pragma unroll
        for (int mi = 0; mi < 4; ++mi)
            #pragma unroll
            for (int nj = 0; nj < 4; ++nj)
                acc[mi][nj] = __builtin_amdgcn_mfma_f32_16x16x32_bf16(
                    af[mi], bfr[nj], acc[mi][nj], 0, 0, 0);

        __syncthreads();   // drains DMA (next tile ready) + all reads of cur done
        cur ^= 1;
    }

    #pragma unroll
    for (int mi = 0; mi < 4; ++mi)
        #pragma unroll
        for (int nj = 0; nj < 4; ++nj) {
            const int row = m0 + wm * 64 + mi * 16 + lq * 4;
            const int col = n0 + wn * 64 + nj * 16 + l16;
            const float bb = bias[col];
            if constexpr (TRANSV) {
                unsigned short o[4];
                #pragma unroll
                for (int r = 0; r < 4; ++r)
                    o[r] = f2bf((acc[mi][nj][r] + bb) * scale);
                const int bb_ = row >> 11, ss = row & (SEQ - 1);   // b, s
                unsigned short* dst = (unsigned short*)Y +
                    ((size_t)(bb_ * NHEADS + (col >> 6)) * HD + (col & 63)) * SEQ + ss;
                *(bf16x4*)dst = *(const bf16x4*)o;
            } else {
                #pragma unroll
                for (int r = 0; r < 4; ++r)
                    st_o(&Y[(size_t)(row + r) * DIM + col],
                         (acc[mi][nj][r] + bb) * scale);
            }
        }
}

template <typename TY, bool TRANSV = false>
__global__ __launch_bounds__(256) void gemm_a16(
    const unsigned short* __restrict__ A, const unsigned short* __restrict__ Wt,
    const float* __restrict__ bias, TY* __restrict__ Y, float scale)
{
    __shared__ unsigned short As[2 * 128 * 32];
    __shared__ unsigned short Bs[2 * 128 * 32];
    gemm_body<TY, TRANSV>(A, Wt, bias, Y, scale, As, Bs);
}

// Fused V+Q+K projections: blockIdx.z selects the unit. 1536 blocks ->
// full-chip TLP for the whole projection phase. All reads/writes of the
// three units are disjoint buffers (qf goes to d_out scratch).
__global__ __launch_bounds__(256) void gemm_qkv(
    const unsigned short* Av, const unsigned short* Wtv, const float* bv_,
    unsigned short* Yv,
    const unsigned short* Aq, const unsigned short* Wtq, const float* bq_,
    unsigned short* Yq,
    const unsigned short* Ak, const unsigned short* Wtk, const float* bk_,
    unsigned short* Yk)
{
    __shared__ unsigned short As[2 * 128 * 32];
    __shared__ unsigned short Bs[2 * 128 * 32];
    const int z = blockIdx.z;
    if (z == 0)
        gemm_body<unsigned short, true >(Av, Wtv, bv_, Yv, 1.0f,   As, Bs);
    else if (z == 1)
        gemm_body<unsigned short, false>(Aq, Wtq, bq_, Yq, QSCALE, As, Bs);
    else
        gemm_body<unsigned short, false>(Ak, Wtk, bk_, Yk, 1.0f,   As, Bs);
}

// ---------- MFMA flash attention v12 ----------
// qf: pre-scaled bf16 [B,S,DIM] (d_out scratch); kf: bf16 [B,S,DIM];
// vt: bf16 [B*H][64][S]; ctx -> separate buffer.
// v12 = round-9 per-wave inner loop (verified), QBLK 64 -> 128 with 8
// waves (512 threads): each wave still owns 16 q-rows and stages exactly
// one K-chunk + one V-chunk per iter (ci = wv). Blocks halve to 1024 ->
// K/V L2 traffic and barrier-slots per q-row halve; 48 KB LDS -> 3 blocks
// x 8 waves = 24 waves/CU. Flat LDS array; O-epilogue reuses its front
// 18.4 KB after the final barrier.
__global__ __launch_bounds__(512) void attn_mfma(
    const unsigned short* __restrict__ qbuf, const unsigned short* __restrict__ kbuf,
    const unsigned short* __restrict__ vtb, unsigned short* __restrict__ ctx)
{
    // [0,8192)       K double-buffer  [buf][s][d], granule-swizzled
    // [8192,16384)   V double-buffer  [buf][d][s], granule-swizzled
    // [16384,24576)  Q [128][64], granule-swizzled
    __shared__ unsigned short lds[24576];   // 48 KB

    const int t = threadIdx.x;
    const int lane = t & 63, wv = t >> 6;           // 8 waves
    const int l16 = lane & 15, lq = lane >> 4;
    const int l7 = l16 & 7;
    const int lqh = lq >> 1, lql4 = (lq & 1) * 4;

    // XCD swizzle (bijective): lin in [0,1024); all 16 q-blocks of a (b,h)
    // share lin%8 -> one XCD's L2 holds that (b,h)'s K/V.
    const unsigned lin  = (blockIdx.z * gridDim.y + blockIdx.y) * gridDim.x + blockIdx.x;
    const unsigned xcd  = lin & 7, slot = lin >> 3;          // slot in [0,128)
    const unsigned bh   = ((slot >> 4) << 3) | xcd;          // [0,64)
    const int b = (int)(bh >> 4), h = (int)(bh & 15);
    const int q0 = (int)(slot & 15) * 128;

    const size_t base  = ((size_t)b * SEQ) * DIM + h * HD;
    const size_t vbase = ((size_t)(b * NHEADS + h)) * HD * SEQ;

    // async16 staging geometry: chunk = 8 rows x 128B; lane l covers
    // row rl = l>>3, dest granule l&7. Source granule pre-swizzled by
    // XOR with (row&7) so reads use the same involution.
    const int rl   = lane >> 3;
    const int gcol = ((lane & 7) ^ rl) << 3;   // source col offset (elems)

    {   // stage Q tile [128][64], swizzled plain stores (wave-local rows)
        const int r = t >> 2, c = (t & 3) * 16;       // r in wave's own 16 rows
        const int g0 = c >> 3, rx = r & 7;
        const unsigned short* src = qbuf + base + (size_t)(q0 + r) * DIM + c;
        *(short8*)&lds[16384 + r * 64 + ((g0 ^ rx) << 3)]       = *(const short8*)src;
        *(short8*)&lds[16384 + r * 64 + (((g0 + 1) ^ rx) << 3)] = *(const short8*)(src + 8);
    }
    // Q fragments (same XOR involution); B-operand of swapped QK
    const int qrow = wv * 16 + l16;                  // [0,128)
    const short8 qf0 = *(const short8*)&lds[16384 + qrow * 64 + ((lq ^ l7) << 3)];
    const short8 qf1 = *(const short8*)&lds[16384 + qrow * 64 + (((4 + lq) ^ l7) << 3)];

    float l_acc = 0.f;
    f32x4 O[4] = {};

    // prologue: stage K/V tile 0 into buffer 0 (1 K-chunk + 1 V-chunk/wave)
    async16(kbuf + base + (size_t)(wv * 8 + rl) * DIM + gcol, lds + wv * 512);
    async16(vtb + vbase + (size_t)(wv * 8 + rl) * SEQ + gcol, lds + 8192 + wv * 512);
    __syncthreads();   // vmcnt drained before barrier -> tile 0 resident

    int cur = 0;
    for (int s0 = 0; s0 < SEQ; s0 += 64) {
        const unsigned short* Kc = lds + cur * 4096;
        const unsigned short* Vc = lds + 8192 + cur * 4096;

        // issue next-tile DMA first; latency hides under QK+softmax+PV
        if (s0 + 64 < SEQ) {
            async16(kbuf + base + (size_t)(s0 + 64 + wv * 8 + rl) * DIM + gcol,
                    lds + (cur ^ 1) * 4096 + wv * 512);
            async16(vtb + vbase + (size_t)(wv * 8 + rl) * SEQ + s0 + 64 + gcol,
                    lds + 8192 + (cur ^ 1) * 4096 + wv * 512);
        }

        // S'^T = K Q^T : C[row = s = lq*4+r (per ti), col = q = l16]
        f32x4 sa[4] = {};
        __builtin_amdgcn_s_setprio(1);
        #pragma unroll
        for (int ti = 0; ti < 4; ++ti) {
            const int rr = ti * 16 + l16;
            const short8 kf0 = *(const short8*)(Kc + rr * 64 + ((lq ^ l7) << 3));
            const short8 kf1 = *(const short8*)(Kc + rr * 64 + (((4 + lq) ^ l7) << 3));
            sa[ti] = __builtin_amdgcn_mfma_f32_16x16x32_bf16(kf0, qf0, sa[ti], 0, 0, 0);
            sa[ti] = __builtin_amdgcn_mfma_f32_16x16x32_bf16(kf1, qf1, sa[ti], 0, 0, 0);
        }
        __builtin_amdgcn_s_setprio(0);

        // p = 2^s' in-register; this IS the 16x16x16 A-frag (k = lq*4+e)
        __builtin_amdgcn_s_setprio(1);
        #pragma unroll
        for (int ti = 0; ti < 4; ++ti) {
            const float v0 = __builtin_amdgcn_exp2f(sa[ti][0]);
            const float v1 = __builtin_amdgcn_exp2f(sa[ti][1]);
            const float v2 = __builtin_amdgcn_exp2f(sa[ti][2]);
            const float v3 = __builtin_amdgcn_exp2f(sa[ti][3]);
            l_acc += (v0 + v1) + (v2 + v3);
            unsigned pw[2] = { pk2bf(v0, v1), pk2bf(v2, v3) };
            bf16x4 pa;
            __builtin_memcpy(&pa, pw, 8);
            #pragma unroll
            for (int dt = 0; dt < 4; ++dt) {
                const int vr = dt * 16 + l16;
                const bf16x4 vb = *(const bf16x4*)(
                    Vc + vr * 64 + (((2 * ti + lqh) ^ l7) << 3) + lql4);
                O[dt] = __builtin_amdgcn_mfma_f32_16x16x16bf16_1k(pa, vb, O[dt], 0, 0, 0);
            }
        }
        __builtin_amdgcn_s_setprio(0);

        __syncthreads();   // drains DMA (next tile ready) + all reads of cur done
        cur ^= 1;
    }

    // row sums: lane partial covers q = wv*16+l16 over s ≡ {lq*4+0..3} (+16k);
    // reduce across the 4 lq groups -> every lane holds S(q = wv*16+l16).
    l_acc += __shfl_xor(l_acc, 16);
    l_acc += __shfl_xor(l_acc, 32);

    // O rows are q = wv*16 + lq*4 + r -> fetch that row's sum from lane lq*4+r.
    unsigned short (*Ol)[72] = (unsigned short(*)[72])lds;   // 128x72 = 18.4 KB
    #pragma unroll
    for (int r = 0; r < 4; ++r) {
        const float inv = 1.0f / __shfl(l_acc, lq * 4 + r);
        const int orow = wv * 16 + lq * 4 + r;               // [0,128)
        #pragma unroll
        for (int dt = 0; dt < 4; ++dt)
            Ol[orow][dt * 16 + l16] = f2bf(O[dt][r] * inv);
    }
    __syncthreads();
    {
        const int r = t >> 2, c = (t & 3) * 16;              // r in [0,128)
        unsigned short* dst = ctx + base + (size_t)(q0 + r) * DIM + c;
        *(short8*)dst       = *(const short8*)&Ol[r][c];
        *(short8*)(dst + 8) = *(const short8*)&Ol[r][c + 8];
    }
}

extern "C" void kernel_launch(void* const* d_in, const int* in_sizes, int n_in,
                              void* d_out, int out_size, void* d_ws, size_t ws_size,
                              hipStream_t stream) {
    const float* Q  = (const float*)d_in[0];
    const float* K  = (const float*)d_in[1];
    const float* V  = (const float*)d_in[2];
    const float* Wq = (const float*)d_in[3];
    const float* bq = (const float*)d_in[4];
    const float* Wk = (const float*)d_in[5];
    const float* bk = (const float*)d_in[6];
    const float* Wv = (const float*)d_in[7];
    const float* bv = (const float*)d_in[8];
    const float* Wo = (const float*)d_in[9];
    const float* bo = (const float*)d_in[10];
    float* out = (float*)d_out;

    // ws: 4 weights (2 MB ea) + 5 x 16 MB buffers = 88 MB.
    // Buffer plan (lifetimes disjoint in stream order; every byte rewritten
    // every launch before any read -> replay-safe):
    //   bufA: vb -> ctx        bufB: kb        bufC: qb
    //   bufD: kf               bufE: vt
    //   d_out: qf scratch (bf16, first 16 MB) -> final f32 output
    const size_t eW = (size_t)DIM * DIM;     // 1M elems
    const size_t eB = (size_t)M_TOT * DIM;   // 8M elems
    unsigned short* p   = (unsigned short*)d_ws;
    unsigned short* wtq = p; p += eW;
    unsigned short* wtk = p; p += eW;
    unsigned short* wtv = p; p += eW;
    unsigned short* wto = p; p += eW;
    unsigned short* bufA = p; p += eB;
    unsigned short* bufB = p; p += eB;
    unsigned short* bufC = p; p += eB;
    unsigned short* bufD = p; p += eB;
    unsigned short* bufE = p;
    unsigned short* qfs = (unsigned short*)out;   // d_out scratch

    wcvt4<<<dim3(32, 32, 4), 256, 0, stream>>>(Wq, Wk, Wv, Wo, wtq, wtk, wtv, wto);

    const int cvt_blocks = (int)(eB / (256 * 16));   // 2048
    cvt3<<<dim3(cvt_blocks, 3), 256, 0, stream>>>(V, Q, K, bufA, bufC, bufB);

    // fused V+Q+K projections: reads {bufA,bufC,bufB,wt*}, writes {bufE,qfs,bufD}
    gemm_qkv<<<dim3(DIM / 128, M_TOT / 128, 3), 256, 0, stream>>>(
        bufA, wtv, bv, bufE,     // z=0: vt (TRANSV epilogue)
        bufC, wtq, bq, qfs,      // z=1: qf -> d_out scratch
        bufB, wtk, bk, bufD);    // z=2: kf

    attn_mfma<<<dim3(SEQ / 128, NHEADS, BATCH), 512, 0, stream>>>(qfs, bufD, bufE, bufA);

    gemm_a16<float><<<dim3(DIM / 128, M_TOT / 128), 256, 0, stream>>>(
        bufA, wto, bo, out, 1.0f);
}